// Round 1
// baseline (169.629 us; speedup 1.0000x reference)
//
#include <hip/hip_runtime.h>

#define NPIX (384*384)        // 147456
#define NSAMP 32
#define ROWS 64               // 32 region rows + 32 affinity rows
#define BINS 1024
#define THREADS 256
#define BLKROW 36
#define EPB (NPIX / BLKROW)   // 4096 elements per block
#define STATS_STRIDE 16
// stats slots (per row): 0=n_pos(u32) 1=pos_sum(f32) 2=k(u32) 3=b1(u32)
// 4=cnt_above1(u32) 5=sum_above1(f32) 6=kprime(u32, 0xFFFFFFFF => no negatives)
// 8=row_result(f32)

__global__ __launch_bounds__(THREADS) void k_hist1(
    const float* __restrict__ gt_r, const float* __restrict__ gt_a,
    const float* __restrict__ pr_r, const float* __restrict__ pr_a,
    const float* __restrict__ conf,
    unsigned int* __restrict__ h1c, float* __restrict__ h1s,
    unsigned int* __restrict__ stats_u, float* __restrict__ stats_f)
{
    __shared__ unsigned int s_cnt[BINS];
    __shared__ float s_sum[BINS];
    __shared__ unsigned int s_pc;
    __shared__ float s_ps;
    const int tid = threadIdx.x;
    const int row = blockIdx.y;
    const int samp = row & (NSAMP - 1);
    const float* gt = (row < NSAMP) ? gt_r : gt_a;
    const float* pr = (row < NSAMP) ? pr_r : pr_a;

    for (int i = tid; i < BINS; i += THREADS) { s_cnt[i] = 0u; s_sum[i] = 0.f; }
    if (tid == 0) { s_pc = 0u; s_ps = 0.f; }
    __syncthreads();

    size_t base = (size_t)samp * NPIX + (size_t)blockIdx.x * EPB;
    unsigned int pc = 0; float ps = 0.f;
    #pragma unroll
    for (int it = 0; it < EPB / (THREADS * 4); ++it) {
        size_t idx = base + (size_t)it * THREADS * 4 + (size_t)tid * 4;
        float4 g = *(const float4*)(gt + idx);
        float4 p = *(const float4*)(pr + idx);
        float4 c = *(const float4*)(conf + idx);
        float gv[4] = {g.x, g.y, g.z, g.w};
        float pv[4] = {p.x, p.y, p.z, p.w};
        float cv[4] = {c.x, c.y, c.z, c.w};
        #pragma unroll
        for (int j = 0; j < 4; ++j) {
            float d = pv[j] - gv[j];
            float l = d * d * cv[j];
            if (gv[j] >= 0.1f) { pc++; ps += l; }
            else {
                unsigned bin = __float_as_uint(l) >> 20;  // l in [0,1) -> bin <= 1015
                atomicAdd(&s_cnt[bin], 1u);
                atomicAdd(&s_sum[bin], l);
            }
        }
    }
    // wave-reduce the positive accumulators, then one LDS atomic per wave
    for (int off = 32; off; off >>= 1) {
        pc += __shfl_down(pc, off);
        ps += __shfl_down(ps, off);
    }
    if ((tid & 63) == 0) { atomicAdd(&s_pc, pc); atomicAdd(&s_ps, ps); }
    __syncthreads();

    for (int i = tid; i < BINS; i += THREADS) {
        unsigned c = s_cnt[i];
        if (c) {
            atomicAdd(&h1c[row * BINS + i], c);
            atomicAdd(&h1s[row * BINS + i], s_sum[i]);
        }
    }
    if (tid == 0) {
        if (s_pc) atomicAdd(&stats_u[row * STATS_STRIDE + 0], s_pc);
        if (s_ps != 0.f) atomicAdd(&stats_f[row * STATS_STRIDE + 1], s_ps);
    }
}

__global__ __launch_bounds__(THREADS) void k_sel1(
    const unsigned int* __restrict__ h1c, const float* __restrict__ h1s,
    unsigned int* __restrict__ stats_u, float* __restrict__ stats_f)
{
    __shared__ unsigned int s_cnt[BINS];
    __shared__ float s_sum[BINS];
    const int row = blockIdx.x, tid = threadIdx.x;
    for (int i = tid; i < BINS; i += THREADS) {
        s_cnt[i] = h1c[row * BINS + i];
        s_sum[i] = h1s[row * BINS + i];
    }
    __syncthreads();
    if (tid == 0) {
        unsigned n_pos = stats_u[row * STATS_STRIDE + 0];
        unsigned n_neg = NPIX - n_pos;
        unsigned k;
        if (n_pos > 0u) {
            k = 3u * n_pos;
            if (k > n_neg) k = n_neg;
            if (k < 1u) k = 1u;
        } else {
            k = 500u;   // fallback: top-500 over all pixels (all are "negatives" here)
        }
        stats_u[row * STATS_STRIDE + 2] = k;
        if (n_neg == 0u) { stats_u[row * STATS_STRIDE + 6] = 0xFFFFFFFFu; return; }
        unsigned cum = 0; float sum = 0.f; int b1 = 0;
        for (int b = BINS - 1; b >= 0; --b) {
            unsigned c = s_cnt[b];
            if (cum + c >= k) { b1 = b; break; }
            cum += c; sum += s_sum[b];
        }
        stats_u[row * STATS_STRIDE + 3] = (unsigned)b1;
        stats_u[row * STATS_STRIDE + 4] = cum;
        stats_f[row * STATS_STRIDE + 5] = sum;
        stats_u[row * STATS_STRIDE + 6] = k - cum;   // k' >= 1
    }
}

__global__ __launch_bounds__(THREADS) void k_hist2(
    const float* __restrict__ gt_r, const float* __restrict__ gt_a,
    const float* __restrict__ pr_r, const float* __restrict__ pr_a,
    const float* __restrict__ conf,
    unsigned int* __restrict__ h2c, float* __restrict__ h2s,
    const unsigned int* __restrict__ stats_u)
{
    __shared__ unsigned int s_cnt[BINS];
    __shared__ float s_sum[BINS];
    const int tid = threadIdx.x;
    const int row = blockIdx.y;
    const unsigned kprime = stats_u[row * STATS_STRIDE + 6];
    if (kprime == 0xFFFFFFFFu) return;      // uniform per block
    const unsigned b1 = stats_u[row * STATS_STRIDE + 3];
    const int samp = row & (NSAMP - 1);
    const float* gt = (row < NSAMP) ? gt_r : gt_a;
    const float* pr = (row < NSAMP) ? pr_r : pr_a;

    for (int i = tid; i < BINS; i += THREADS) { s_cnt[i] = 0u; s_sum[i] = 0.f; }
    __syncthreads();

    size_t base = (size_t)samp * NPIX + (size_t)blockIdx.x * EPB;
    #pragma unroll
    for (int it = 0; it < EPB / (THREADS * 4); ++it) {
        size_t idx = base + (size_t)it * THREADS * 4 + (size_t)tid * 4;
        float4 g = *(const float4*)(gt + idx);
        float4 p = *(const float4*)(pr + idx);
        float4 c = *(const float4*)(conf + idx);
        float gv[4] = {g.x, g.y, g.z, g.w};
        float pv[4] = {p.x, p.y, p.z, p.w};
        float cv[4] = {c.x, c.y, c.z, c.w};
        #pragma unroll
        for (int j = 0; j < 4; ++j) {
            float d = pv[j] - gv[j];
            float l = d * d * cv[j];
            if (gv[j] < 0.1f) {
                unsigned bits = __float_as_uint(l);
                if ((bits >> 20) == b1) {
                    unsigned bin2 = (bits >> 10) & 1023u;
                    atomicAdd(&s_cnt[bin2], 1u);
                    atomicAdd(&s_sum[bin2], l);
                }
            }
        }
    }
    __syncthreads();
    for (int i = tid; i < BINS; i += THREADS) {
        unsigned c = s_cnt[i];
        if (c) {
            atomicAdd(&h2c[row * BINS + i], c);
            atomicAdd(&h2s[row * BINS + i], s_sum[i]);
        }
    }
}

__global__ __launch_bounds__(THREADS) void k_sel2(
    const unsigned int* __restrict__ h2c, const float* __restrict__ h2s,
    const unsigned int* __restrict__ stats_u, float* __restrict__ stats_f)
{
    __shared__ unsigned int s_cnt[BINS];
    __shared__ float s_sum[BINS];
    const int row = blockIdx.x, tid = threadIdx.x;
    for (int i = tid; i < BINS; i += THREADS) {
        s_cnt[i] = h2c[row * BINS + i];
        s_sum[i] = h2s[row * BINS + i];
    }
    __syncthreads();
    if (tid == 0) {
        unsigned n_pos = stats_u[row * STATS_STRIDE + 0];
        unsigned k     = stats_u[row * STATS_STRIDE + 2];
        float pos_part = (n_pos > 0u) ? stats_f[row * STATS_STRIDE + 1] / (float)n_pos : 0.f;
        unsigned kprime = stats_u[row * STATS_STRIDE + 6];
        float res;
        if (kprime == 0xFFFFFFFFu) {
            res = pos_part - 1.f;   // no negatives: neg_loss = sentinel -1
        } else {
            unsigned cum = 0; float sum = 0.f; int b2 = 0;
            for (int b = BINS - 1; b >= 0; --b) {
                unsigned c = s_cnt[b];
                if (cum + c >= kprime) { b2 = b; break; }
                cum += c; sum += s_sum[b];
            }
            unsigned kpp = kprime - cum;           // 1 <= kpp <= cnt[b2]
            float mean = s_sum[b2] / (float)s_cnt[b2];
            float topk = stats_f[row * STATS_STRIDE + 5] + sum + (float)kpp * mean;
            res = pos_part + topk / (float)k;
        }
        stats_f[row * STATS_STRIDE + 8] = res;
    }
}

__global__ void k_final(const float* __restrict__ stats_f, float* __restrict__ out)
{
    int t = threadIdx.x;   // 64 threads, one wave
    float v = stats_f[t * STATS_STRIDE + 8];
    for (int off = 32; off; off >>= 1) v += __shfl_down(v, off);
    if (t == 0) out[0] = v / (float)NSAMP;
}

extern "C" void kernel_launch(void* const* d_in, const int* in_sizes, int n_in,
                              void* d_out, int out_size, void* d_ws, size_t ws_size,
                              hipStream_t stream)
{
    (void)in_sizes; (void)n_in; (void)out_size; (void)ws_size;
    const float* gt_r = (const float*)d_in[0];
    const float* gt_a = (const float*)d_in[1];
    const float* pr_r = (const float*)d_in[2];
    const float* pr_a = (const float*)d_in[3];
    const float* conf = (const float*)d_in[4];

    char* ws = (char*)d_ws;
    unsigned int* h1c = (unsigned int*)(ws + 0 * ROWS * BINS * 4);
    float*        h1s = (float*)       (ws + 1 * (size_t)ROWS * BINS * 4);
    unsigned int* h2c = (unsigned int*)(ws + 2 * (size_t)ROWS * BINS * 4);
    float*        h2s = (float*)       (ws + 3 * (size_t)ROWS * BINS * 4);
    unsigned int* stats_u = (unsigned int*)(ws + 4 * (size_t)ROWS * BINS * 4);
    float*        stats_f = (float*)       (ws + 4 * (size_t)ROWS * BINS * 4);
    size_t used = 4 * (size_t)ROWS * BINS * 4 + (size_t)ROWS * STATS_STRIDE * 4;
    hipMemsetAsync(d_ws, 0, used, stream);

    dim3 gridA(BLKROW, ROWS);
    k_hist1<<<gridA, THREADS, 0, stream>>>(gt_r, gt_a, pr_r, pr_a, conf,
                                           h1c, h1s, stats_u, stats_f);
    k_sel1<<<ROWS, THREADS, 0, stream>>>(h1c, h1s, stats_u, stats_f);
    k_hist2<<<gridA, THREADS, 0, stream>>>(gt_r, gt_a, pr_r, pr_a, conf,
                                           h2c, h2s, stats_u);
    k_sel2<<<ROWS, THREADS, 0, stream>>>(h2c, h2s, stats_u, stats_f);
    k_final<<<1, 64, 0, stream>>>(stats_f, (float*)d_out);
}

// Round 2
// 90.594 us; speedup vs baseline: 1.8724x; 1.8724x over previous
//
#include <hip/hip_runtime.h>

#define NPIX (384*384)        // 147456
#define NSAMP 32
#define ROWS 64               // 32 region rows + 32 affinity rows
#define BINS 1024
#define THREADS 256
#define BLKROW 36
#define EPB (NPIX / BLKROW)   // 4096 elements per block
#define STATS_STRIDE 16
// stats slots (per row): 0=n_pos(u32) 1=pos_sum(f32) 2=k(u32) 3=b1(u32)
// 4=cnt_above1(u32) 5=sum_above1(f32) 6=kprime(u32, 0xFFFFFFFF => no negatives)
// 8=row_result(f32)

__global__ __launch_bounds__(THREADS) void k_hist1(
    const float* __restrict__ gt_r, const float* __restrict__ gt_a,
    const float* __restrict__ pr_r, const float* __restrict__ pr_a,
    const float* __restrict__ conf,
    unsigned int* __restrict__ h1c, float* __restrict__ h1s,
    unsigned int* __restrict__ stats_u, float* __restrict__ stats_f)
{
    __shared__ unsigned int s_cnt[BINS];
    __shared__ float s_sum[BINS];
    __shared__ unsigned int s_pc;
    __shared__ float s_ps;
    const int tid = threadIdx.x;
    const int row = blockIdx.y;
    const int samp = row & (NSAMP - 1);
    const float* gt = (row < NSAMP) ? gt_r : gt_a;
    const float* pr = (row < NSAMP) ? pr_r : pr_a;

    for (int i = tid; i < BINS; i += THREADS) { s_cnt[i] = 0u; s_sum[i] = 0.f; }
    if (tid == 0) { s_pc = 0u; s_ps = 0.f; }
    __syncthreads();

    size_t base = (size_t)samp * NPIX + (size_t)blockIdx.x * EPB;
    unsigned int pc = 0; float ps = 0.f;
    #pragma unroll
    for (int it = 0; it < EPB / (THREADS * 4); ++it) {
        size_t idx = base + (size_t)it * THREADS * 4 + (size_t)tid * 4;
        float4 g = *(const float4*)(gt + idx);
        float4 p = *(const float4*)(pr + idx);
        float4 c = *(const float4*)(conf + idx);
        float gv[4] = {g.x, g.y, g.z, g.w};
        float pv[4] = {p.x, p.y, p.z, p.w};
        float cv[4] = {c.x, c.y, c.z, c.w};
        #pragma unroll
        for (int j = 0; j < 4; ++j) {
            float d = pv[j] - gv[j];
            float l = d * d * cv[j];
            if (gv[j] >= 0.1f) { pc++; ps += l; }
            else {
                unsigned bin = __float_as_uint(l) >> 20;  // l in [0,1) -> bin <= 1015
                atomicAdd(&s_cnt[bin], 1u);
                atomicAdd(&s_sum[bin], l);
            }
        }
    }
    // wave-reduce the positive accumulators, then one LDS atomic per wave
    for (int off = 32; off; off >>= 1) {
        pc += __shfl_down(pc, off);
        ps += __shfl_down(ps, off);
    }
    if ((tid & 63) == 0) { atomicAdd(&s_pc, pc); atomicAdd(&s_ps, ps); }
    __syncthreads();

    for (int i = tid; i < BINS; i += THREADS) {
        unsigned c = s_cnt[i];
        if (c) {
            atomicAdd(&h1c[row * BINS + i], c);
            atomicAdd(&h1s[row * BINS + i], s_sum[i]);
        }
    }
    if (tid == 0) {
        if (s_pc) atomicAdd(&stats_u[row * STATS_STRIDE + 0], s_pc);
        if (s_ps != 0.f) atomicAdd(&stats_f[row * STATS_STRIDE + 1], s_ps);
    }
}

// Parallel descending-order boundary search over a 1024-bin histogram.
// Each thread owns 4 consecutive descending ranks (rank 0 = bin 1023).
// Finds the unique rank where cumulative count (strictly above) < k <= cum+c.
// Outputs via pointers: bin index, count above, float-sum above, and the
// owning bin's count/sum (valid only in the matching thread, which also
// gets match=true).
__device__ __forceinline__ void suffix_scan_match(
    const unsigned int* __restrict__ hc, const float* __restrict__ hs,
    int row, unsigned k,
    bool* match, int* out_bin, unsigned* out_cum, float* out_sum,
    unsigned* out_c, float* out_s)
{
    const int tid = threadIdx.x;
    unsigned c[4]; float s[4];
    #pragma unroll
    for (int j = 0; j < 4; ++j) {
        int bin = BINS - 1 - (tid * 4 + j);
        c[j] = hc[row * BINS + bin];
        s[j] = hs[row * BINS + bin];
    }
    unsigned tc = c[0] + c[1] + c[2] + c[3];
    float    ts = s[0] + s[1] + s[2] + s[3];
    // wave inclusive scan
    unsigned lane = tid & 63, w = tid >> 6;
    unsigned ic = tc; float is = ts;
    #pragma unroll
    for (int off = 1; off < 64; off <<= 1) {
        unsigned uc = __shfl_up(ic, off);
        float    us = __shfl_up(is, off);
        if (lane >= off) { ic += uc; is += us; }
    }
    __shared__ unsigned wtc[4]; __shared__ float wts[4];
    if (lane == 63) { wtc[w] = ic; wts[w] = is; }
    __syncthreads();
    unsigned woc = 0; float wos = 0.f;
    for (unsigned i = 0; i < w; ++i) { woc += wtc[i]; wos += wts[i]; }
    unsigned before_c = woc + ic - tc;  // exclusive prefix (count above my first rank)
    float    before_s = wos + is - ts;

    *match = false;
    #pragma unroll
    for (int j = 0; j < 4; ++j) {
        if (before_c < k && before_c + c[j] >= k) {
            *match = true;
            *out_bin = BINS - 1 - (tid * 4 + j);
            *out_cum = before_c;
            *out_sum = before_s;
            *out_c = c[j];
            *out_s = s[j];
        }
        before_c += c[j]; before_s += s[j];
    }
}

__global__ __launch_bounds__(THREADS) void k_sel1(
    const unsigned int* __restrict__ h1c, const float* __restrict__ h1s,
    unsigned int* __restrict__ stats_u, float* __restrict__ stats_f)
{
    const int row = blockIdx.x, tid = threadIdx.x;
    unsigned n_pos = stats_u[row * STATS_STRIDE + 0];
    unsigned n_neg = NPIX - n_pos;
    unsigned k;
    if (n_pos > 0u) {
        k = 3u * n_pos;
        if (k > n_neg) k = n_neg;
        if (k < 1u) k = 1u;
    } else {
        k = 500u;   // fallback: top-500 over all pixels (all are "negatives" here)
    }
    if (tid == 0) stats_u[row * STATS_STRIDE + 2] = k;
    if (n_neg == 0u) {
        if (tid == 0) stats_u[row * STATS_STRIDE + 6] = 0xFFFFFFFFu;
        return;
    }
    bool match; int b1; unsigned cum, cb; float sum, sb;
    suffix_scan_match(h1c, h1s, row, k, &match, &b1, &cum, &sum, &cb, &sb);
    if (match) {
        stats_u[row * STATS_STRIDE + 3] = (unsigned)b1;
        stats_u[row * STATS_STRIDE + 4] = cum;
        stats_f[row * STATS_STRIDE + 5] = sum;
        stats_u[row * STATS_STRIDE + 6] = k - cum;   // k' >= 1
    }
}

__global__ __launch_bounds__(THREADS) void k_hist2(
    const float* __restrict__ gt_r, const float* __restrict__ gt_a,
    const float* __restrict__ pr_r, const float* __restrict__ pr_a,
    const float* __restrict__ conf,
    unsigned int* __restrict__ h2c, float* __restrict__ h2s,
    const unsigned int* __restrict__ stats_u)
{
    __shared__ unsigned int s_cnt[BINS];
    __shared__ float s_sum[BINS];
    const int tid = threadIdx.x;
    const int row = blockIdx.y;
    const unsigned kprime = stats_u[row * STATS_STRIDE + 6];
    if (kprime == 0xFFFFFFFFu) return;      // uniform per block
    const unsigned b1 = stats_u[row * STATS_STRIDE + 3];
    const int samp = row & (NSAMP - 1);
    const float* gt = (row < NSAMP) ? gt_r : gt_a;
    const float* pr = (row < NSAMP) ? pr_r : pr_a;

    for (int i = tid; i < BINS; i += THREADS) { s_cnt[i] = 0u; s_sum[i] = 0.f; }
    __syncthreads();

    size_t base = (size_t)samp * NPIX + (size_t)blockIdx.x * EPB;
    #pragma unroll
    for (int it = 0; it < EPB / (THREADS * 4); ++it) {
        size_t idx = base + (size_t)it * THREADS * 4 + (size_t)tid * 4;
        float4 g = *(const float4*)(gt + idx);
        float4 p = *(const float4*)(pr + idx);
        float4 c = *(const float4*)(conf + idx);
        float gv[4] = {g.x, g.y, g.z, g.w};
        float pv[4] = {p.x, p.y, p.z, p.w};
        float cv[4] = {c.x, c.y, c.z, c.w};
        #pragma unroll
        for (int j = 0; j < 4; ++j) {
            float d = pv[j] - gv[j];
            float l = d * d * cv[j];
            if (gv[j] < 0.1f) {
                unsigned bits = __float_as_uint(l);
                if ((bits >> 20) == b1) {
                    unsigned bin2 = (bits >> 10) & 1023u;
                    atomicAdd(&s_cnt[bin2], 1u);
                    atomicAdd(&s_sum[bin2], l);
                }
            }
        }
    }
    __syncthreads();
    for (int i = tid; i < BINS; i += THREADS) {
        unsigned c = s_cnt[i];
        if (c) {
            atomicAdd(&h2c[row * BINS + i], c);
            atomicAdd(&h2s[row * BINS + i], s_sum[i]);
        }
    }
}

__global__ __launch_bounds__(THREADS) void k_sel2(
    const unsigned int* __restrict__ h2c, const float* __restrict__ h2s,
    const unsigned int* __restrict__ stats_u, float* __restrict__ stats_f)
{
    const int row = blockIdx.x, tid = threadIdx.x;
    unsigned n_pos = stats_u[row * STATS_STRIDE + 0];
    unsigned k     = stats_u[row * STATS_STRIDE + 2];
    float pos_part = (n_pos > 0u) ? stats_f[row * STATS_STRIDE + 1] / (float)n_pos : 0.f;
    unsigned kprime = stats_u[row * STATS_STRIDE + 6];
    if (kprime == 0xFFFFFFFFu) {
        if (tid == 0) stats_f[row * STATS_STRIDE + 8] = pos_part - 1.f; // sentinel neg_loss
        return;
    }
    bool match; int b2; unsigned cum, cb; float sum, sb;
    suffix_scan_match(h2c, h2s, row, kprime, &match, &b2, &cum, &sum, &cb, &sb);
    if (match) {
        unsigned kpp = kprime - cum;           // 1 <= kpp <= cnt[b2]
        float mean = sb / (float)cb;
        float topk = stats_f[row * STATS_STRIDE + 5] + sum + (float)kpp * mean;
        stats_f[row * STATS_STRIDE + 8] = pos_part + topk / (float)k;
    }
}

__global__ void k_final(const float* __restrict__ stats_f, float* __restrict__ out)
{
    int t = threadIdx.x;   // 64 threads, one wave
    float v = stats_f[t * STATS_STRIDE + 8];
    for (int off = 32; off; off >>= 1) v += __shfl_down(v, off);
    if (t == 0) out[0] = v / (float)NSAMP;
}

extern "C" void kernel_launch(void* const* d_in, const int* in_sizes, int n_in,
                              void* d_out, int out_size, void* d_ws, size_t ws_size,
                              hipStream_t stream)
{
    (void)in_sizes; (void)n_in; (void)out_size; (void)ws_size;
    const float* gt_r = (const float*)d_in[0];
    const float* gt_a = (const float*)d_in[1];
    const float* pr_r = (const float*)d_in[2];
    const float* pr_a = (const float*)d_in[3];
    const float* conf = (const float*)d_in[4];

    char* ws = (char*)d_ws;
    unsigned int* h1c = (unsigned int*)(ws + 0 * (size_t)ROWS * BINS * 4);
    float*        h1s = (float*)       (ws + 1 * (size_t)ROWS * BINS * 4);
    unsigned int* h2c = (unsigned int*)(ws + 2 * (size_t)ROWS * BINS * 4);
    float*        h2s = (float*)       (ws + 3 * (size_t)ROWS * BINS * 4);
    unsigned int* stats_u = (unsigned int*)(ws + 4 * (size_t)ROWS * BINS * 4);
    float*        stats_f = (float*)       (ws + 4 * (size_t)ROWS * BINS * 4);
    size_t used = 4 * (size_t)ROWS * BINS * 4 + (size_t)ROWS * STATS_STRIDE * 4;
    hipMemsetAsync(d_ws, 0, used, stream);

    dim3 gridA(BLKROW, ROWS);
    k_hist1<<<gridA, THREADS, 0, stream>>>(gt_r, gt_a, pr_r, pr_a, conf,
                                           h1c, h1s, stats_u, stats_f);
    k_sel1<<<ROWS, THREADS, 0, stream>>>(h1c, h1s, stats_u, stats_f);
    k_hist2<<<gridA, THREADS, 0, stream>>>(gt_r, gt_a, pr_r, pr_a, conf,
                                           h2c, h2s, stats_u);
    k_sel2<<<ROWS, THREADS, 0, stream>>>(h2c, h2s, stats_u, stats_f);
    k_final<<<1, 64, 0, stream>>>(stats_f, (float*)d_out);
}

// Round 3
// 59.478 us; speedup vs baseline: 2.8519x; 1.5231x over previous
//
#include <hip/hip_runtime.h>

#define NPIX (384*384)        // 147456
#define NSAMP 32
#define ROWS 64               // 32 region rows + 32 affinity rows
#define BINS 1024
#define REPL 4                // histogram replication (same-address conflict fix)
#define THREADS 256
#define BLKROW 36
#define EPB (NPIX / BLKROW)   // 4096 elements per block
#define STATS_STRIDE 16
#define FXSCALE 268435456.0f  // 2^28 fixed-point scale for packed bin sums
#define FXINV   3.7252902984619141e-9
#define MASK46  ((1ULL << 46) - 1)
// stats slots (per row): 0=n_pos(u32) 1=pos_sum(f32) 2=k(u32) 3=b1(u32)
// 4=cnt_above1(u32) 5=sum_above1(f32) 6=kprime(u32, 0xFFFFFFFF => no negatives)
// 8=row_result(f32)

__global__ __launch_bounds__(THREADS) void k_hist1(
    const float* __restrict__ gt_r, const float* __restrict__ gt_a,
    const float* __restrict__ pr_r, const float* __restrict__ pr_a,
    const float* __restrict__ conf,
    unsigned int* __restrict__ h1c, float* __restrict__ h1s,
    unsigned int* __restrict__ stats_u, float* __restrict__ stats_f,
    unsigned int* __restrict__ l_buf)
{
    __shared__ unsigned long long s_hist[BINS * REPL];   // 32 KB, (cnt<<46)|sum_fx
    __shared__ unsigned int s_pc;
    __shared__ float s_ps;
    const int tid = threadIdx.x;
    const int row = blockIdx.y;
    const int samp = row & (NSAMP - 1);
    const float* gt = (row < NSAMP) ? gt_r : gt_a;
    const float* pr = (row < NSAMP) ? pr_r : pr_a;
    const unsigned copy = tid & (REPL - 1);

    for (int i = tid; i < BINS * REPL; i += THREADS) s_hist[i] = 0ULL;
    if (tid == 0) { s_pc = 0u; s_ps = 0.f; }
    __syncthreads();

    size_t base = (size_t)samp * NPIX + (size_t)blockIdx.x * EPB;
    size_t lbase = (size_t)row * NPIX + (size_t)blockIdx.x * EPB;
    unsigned int pc = 0; float ps = 0.f;
    #pragma unroll
    for (int it = 0; it < EPB / (THREADS * 4); ++it) {
        size_t idx = base + (size_t)it * THREADS * 4 + (size_t)tid * 4;
        float4 g = *(const float4*)(gt + idx);
        float4 p = *(const float4*)(pr + idx);
        float4 c = *(const float4*)(conf + idx);
        float gv[4] = {g.x, g.y, g.z, g.w};
        float pv[4] = {p.x, p.y, p.z, p.w};
        float cv[4] = {c.x, c.y, c.z, c.w};
        unsigned lb[4];
        #pragma unroll
        for (int j = 0; j < 4; ++j) {
            float d = pv[j] - gv[j];
            float l = d * d * cv[j];
            if (gv[j] >= 0.1f) {
                pc++; ps += l;
                lb[j] = 0xFFFFFFFFu;                  // sentinel: not a negative
            } else {
                unsigned bits = __float_as_uint(l);
                lb[j] = bits;
                unsigned bin = bits >> 20;            // l in [0,1) -> bin <= 1015
                unsigned long long pk =
                    (1ULL << 46) | (unsigned long long)(unsigned)(l * FXSCALE);
                atomicAdd(&s_hist[(bin << 2) | copy], pk);
            }
        }
        if (l_buf) {
            uint4 st = make_uint4(lb[0], lb[1], lb[2], lb[3]);
            *(uint4*)(l_buf + lbase + (size_t)it * THREADS * 4 + (size_t)tid * 4) = st;
        }
    }
    // wave-reduce the positive accumulators, then one LDS atomic per wave
    for (int off = 32; off; off >>= 1) {
        pc += __shfl_down(pc, off);
        ps += __shfl_down(ps, off);
    }
    if ((tid & 63) == 0) { atomicAdd(&s_pc, pc); atomicAdd(&s_ps, ps); }
    __syncthreads();

    for (int i = tid; i < BINS; i += THREADS) {
        unsigned long long v = s_hist[i << 2] + s_hist[(i << 2) | 1]
                             + s_hist[(i << 2) | 2] + s_hist[(i << 2) | 3];
        if (v) {
            unsigned cnt = (unsigned)(v >> 46);
            float sum = (float)((double)(v & MASK46) * FXINV);
            atomicAdd(&h1c[row * BINS + i], cnt);
            atomicAdd(&h1s[row * BINS + i], sum);
        }
    }
    if (tid == 0) {
        if (s_pc) atomicAdd(&stats_u[row * STATS_STRIDE + 0], s_pc);
        if (s_ps != 0.f) atomicAdd(&stats_f[row * STATS_STRIDE + 1], s_ps);
    }
}

// Parallel descending-order boundary search over a 1024-bin histogram.
// Each thread owns 4 consecutive descending ranks (rank 0 = bin 1023).
// Finds the unique rank where cum (strictly above) < k <= cum+c.
__device__ __forceinline__ void suffix_scan_match(
    const unsigned int* __restrict__ hc, const float* __restrict__ hs,
    int row, unsigned k,
    bool* match, int* out_bin, unsigned* out_cum, float* out_sum,
    unsigned* out_c, float* out_s)
{
    const int tid = threadIdx.x;
    unsigned c[4]; float s[4];
    #pragma unroll
    for (int j = 0; j < 4; ++j) {
        int bin = BINS - 1 - (tid * 4 + j);
        c[j] = hc[row * BINS + bin];
        s[j] = hs[row * BINS + bin];
    }
    unsigned tc = c[0] + c[1] + c[2] + c[3];
    float    ts = s[0] + s[1] + s[2] + s[3];
    unsigned lane = tid & 63, w = tid >> 6;
    unsigned ic = tc; float is = ts;
    #pragma unroll
    for (int off = 1; off < 64; off <<= 1) {
        unsigned uc = __shfl_up(ic, off);
        float    us = __shfl_up(is, off);
        if (lane >= off) { ic += uc; is += us; }
    }
    __shared__ unsigned wtc[4]; __shared__ float wts[4];
    if (lane == 63) { wtc[w] = ic; wts[w] = is; }
    __syncthreads();
    unsigned woc = 0; float wos = 0.f;
    for (unsigned i = 0; i < w; ++i) { woc += wtc[i]; wos += wts[i]; }
    unsigned before_c = woc + ic - tc;  // exclusive prefix (count above my first rank)
    float    before_s = wos + is - ts;

    *match = false;
    #pragma unroll
    for (int j = 0; j < 4; ++j) {
        if (before_c < k && before_c + c[j] >= k) {
            *match = true;
            *out_bin = BINS - 1 - (tid * 4 + j);
            *out_cum = before_c;
            *out_sum = before_s;
            *out_c = c[j];
            *out_s = s[j];
        }
        before_c += c[j]; before_s += s[j];
    }
}

__global__ __launch_bounds__(THREADS) void k_sel1(
    const unsigned int* __restrict__ h1c, const float* __restrict__ h1s,
    unsigned int* __restrict__ stats_u, float* __restrict__ stats_f)
{
    const int row = blockIdx.x, tid = threadIdx.x;
    unsigned n_pos = stats_u[row * STATS_STRIDE + 0];
    unsigned n_neg = NPIX - n_pos;
    unsigned k;
    if (n_pos > 0u) {
        k = 3u * n_pos;
        if (k > n_neg) k = n_neg;
        if (k < 1u) k = 1u;
    } else {
        k = 500u;   // fallback: top-500 over all pixels (all are "negatives" here)
    }
    if (tid == 0) stats_u[row * STATS_STRIDE + 2] = k;
    if (n_neg == 0u) {
        if (tid == 0) stats_u[row * STATS_STRIDE + 6] = 0xFFFFFFFFu;
        return;
    }
    bool match; int b1; unsigned cum, cb; float sum, sb;
    suffix_scan_match(h1c, h1s, row, k, &match, &b1, &cum, &sum, &cb, &sb);
    if (match) {
        stats_u[row * STATS_STRIDE + 3] = (unsigned)b1;
        stats_u[row * STATS_STRIDE + 4] = cum;
        stats_f[row * STATS_STRIDE + 5] = sum;
        stats_u[row * STATS_STRIDE + 6] = k - cum;   // k' >= 1
    }
}

__global__ __launch_bounds__(THREADS) void k_hist2(
    const float* __restrict__ gt_r, const float* __restrict__ gt_a,
    const float* __restrict__ pr_r, const float* __restrict__ pr_a,
    const float* __restrict__ conf,
    unsigned int* __restrict__ h2c, float* __restrict__ h2s,
    const unsigned int* __restrict__ stats_u,
    const unsigned int* __restrict__ l_buf)
{
    __shared__ unsigned int s_cnt[BINS];
    __shared__ float s_sum[BINS];
    const int tid = threadIdx.x;
    const int row = blockIdx.y;
    const unsigned kprime = stats_u[row * STATS_STRIDE + 6];
    if (kprime == 0xFFFFFFFFu) return;      // uniform per block
    const unsigned b1 = stats_u[row * STATS_STRIDE + 3];

    for (int i = tid; i < BINS; i += THREADS) { s_cnt[i] = 0u; s_sum[i] = 0.f; }
    __syncthreads();

    if (l_buf) {
        size_t lbase = (size_t)row * NPIX + (size_t)blockIdx.x * EPB;
        #pragma unroll
        for (int it = 0; it < EPB / (THREADS * 4); ++it) {
            uint4 bv = *(const uint4*)(l_buf + lbase + (size_t)it * THREADS * 4
                                       + (size_t)tid * 4);
            unsigned b[4] = {bv.x, bv.y, bv.z, bv.w};
            #pragma unroll
            for (int j = 0; j < 4; ++j) {
                if ((b[j] >> 20) == b1) {
                    unsigned bin2 = (b[j] >> 10) & 1023u;
                    atomicAdd(&s_cnt[bin2], 1u);
                    atomicAdd(&s_sum[bin2], __uint_as_float(b[j]));
                }
            }
        }
    } else {
        const int samp = row & (NSAMP - 1);
        const float* gt = (row < NSAMP) ? gt_r : gt_a;
        const float* pr = (row < NSAMP) ? pr_r : pr_a;
        size_t base = (size_t)samp * NPIX + (size_t)blockIdx.x * EPB;
        #pragma unroll
        for (int it = 0; it < EPB / (THREADS * 4); ++it) {
            size_t idx = base + (size_t)it * THREADS * 4 + (size_t)tid * 4;
            float4 g = *(const float4*)(gt + idx);
            float4 p = *(const float4*)(pr + idx);
            float4 c = *(const float4*)(conf + idx);
            float gv[4] = {g.x, g.y, g.z, g.w};
            float pv[4] = {p.x, p.y, p.z, p.w};
            float cv[4] = {c.x, c.y, c.z, c.w};
            #pragma unroll
            for (int j = 0; j < 4; ++j) {
                float d = pv[j] - gv[j];
                float l = d * d * cv[j];
                if (gv[j] < 0.1f) {
                    unsigned bits = __float_as_uint(l);
                    if ((bits >> 20) == b1) {
                        unsigned bin2 = (bits >> 10) & 1023u;
                        atomicAdd(&s_cnt[bin2], 1u);
                        atomicAdd(&s_sum[bin2], l);
                    }
                }
            }
        }
    }
    __syncthreads();
    for (int i = tid; i < BINS; i += THREADS) {
        unsigned c = s_cnt[i];
        if (c) {
            atomicAdd(&h2c[row * BINS + i], c);
            atomicAdd(&h2s[row * BINS + i], s_sum[i]);
        }
    }
}

__global__ __launch_bounds__(THREADS) void k_sel2(
    const unsigned int* __restrict__ h2c, const float* __restrict__ h2s,
    const unsigned int* __restrict__ stats_u, float* __restrict__ stats_f)
{
    const int row = blockIdx.x, tid = threadIdx.x;
    unsigned n_pos = stats_u[row * STATS_STRIDE + 0];
    unsigned k     = stats_u[row * STATS_STRIDE + 2];
    float pos_part = (n_pos > 0u) ? stats_f[row * STATS_STRIDE + 1] / (float)n_pos : 0.f;
    unsigned kprime = stats_u[row * STATS_STRIDE + 6];
    if (kprime == 0xFFFFFFFFu) {
        if (tid == 0) stats_f[row * STATS_STRIDE + 8] = pos_part - 1.f; // sentinel
        return;
    }
    bool match; int b2; unsigned cum, cb; float sum, sb;
    suffix_scan_match(h2c, h2s, row, kprime, &match, &b2, &cum, &sum, &cb, &sb);
    if (match) {
        unsigned kpp = kprime - cum;           // 1 <= kpp <= cnt[b2]
        float mean = sb / (float)cb;
        float topk = stats_f[row * STATS_STRIDE + 5] + sum + (float)kpp * mean;
        stats_f[row * STATS_STRIDE + 8] = pos_part + topk / (float)k;
    }
}

__global__ void k_final(const float* __restrict__ stats_f, float* __restrict__ out)
{
    int t = threadIdx.x;   // 64 threads, one wave
    float v = stats_f[t * STATS_STRIDE + 8];
    for (int off = 32; off; off >>= 1) v += __shfl_down(v, off);
    if (t == 0) out[0] = v / (float)NSAMP;
}

extern "C" void kernel_launch(void* const* d_in, const int* in_sizes, int n_in,
                              void* d_out, int out_size, void* d_ws, size_t ws_size,
                              hipStream_t stream)
{
    (void)in_sizes; (void)n_in; (void)out_size;
    const float* gt_r = (const float*)d_in[0];
    const float* gt_a = (const float*)d_in[1];
    const float* pr_r = (const float*)d_in[2];
    const float* pr_a = (const float*)d_in[3];
    const float* conf = (const float*)d_in[4];

    char* ws = (char*)d_ws;
    unsigned int* h1c = (unsigned int*)(ws + 0 * (size_t)ROWS * BINS * 4);
    float*        h1s = (float*)       (ws + 1 * (size_t)ROWS * BINS * 4);
    unsigned int* h2c = (unsigned int*)(ws + 2 * (size_t)ROWS * BINS * 4);
    float*        h2s = (float*)       (ws + 3 * (size_t)ROWS * BINS * 4);
    unsigned int* stats_u = (unsigned int*)(ws + 4 * (size_t)ROWS * BINS * 4);
    float*        stats_f = (float*)       (ws + 4 * (size_t)ROWS * BINS * 4);
    size_t hist_used = 4 * (size_t)ROWS * BINS * 4 + (size_t)ROWS * STATS_STRIDE * 4;

    const size_t L_OFF = 2u << 20;                       // 2 MB, past hist region
    const size_t L_BYTES = (size_t)ROWS * NPIX * 4;      // 37.75 MB
    unsigned int* l_buf = (ws_size >= L_OFF + L_BYTES)
                        ? (unsigned int*)(ws + L_OFF) : nullptr;

    hipMemsetAsync(d_ws, 0, hist_used, stream);          // l_buf fully overwritten

    dim3 gridA(BLKROW, ROWS);
    k_hist1<<<gridA, THREADS, 0, stream>>>(gt_r, gt_a, pr_r, pr_a, conf,
                                           h1c, h1s, stats_u, stats_f, l_buf);
    k_sel1<<<ROWS, THREADS, 0, stream>>>(h1c, h1s, stats_u, stats_f);
    k_hist2<<<gridA, THREADS, 0, stream>>>(gt_r, gt_a, pr_r, pr_a, conf,
                                           h2c, h2s, stats_u, l_buf);
    k_sel2<<<ROWS, THREADS, 0, stream>>>(h2c, h2s, stats_u, stats_f);
    k_final<<<1, 64, 0, stream>>>(stats_f, (float*)d_out);
}

// Round 4
// 55.500 us; speedup vs baseline: 3.0564x; 1.0717x over previous
//
#include <hip/hip_runtime.h>

#define NPIX (384*384)        // 147456
#define NSAMP 32
#define ROWS 64               // 32 region rows + 32 affinity rows
#define BINS 1024
#define REPL 2                // histogram replication (same-address conflict fix)
#define THREADS 256
#define BLKROW 36
#define EPB (NPIX / BLKROW)   // 4096 elements per block
#define STATS_STRIDE 16
#define FXSCALE 268435456.0f  // 2^28 fixed-point scale for packed bin sums
#define FXINV   3.7252902984619141e-9
#define MASK46  ((1ULL << 46) - 1)
// stats slots (per row): 0=n_pos(u32) 1=pos_sum(f32) 2=k(u32) 3=b1(u32)
// 4=cnt_above1(u32) 5=sum_above1(f32) 6=kprime(u32, 0xFFFFFFFF => no negatives)

// Zero the histogram/stats region (uint4-wide) + d_out. Replaces the slow
// rocclr fillBuffer (~39us for 1MB) with a ~2us wide-grid kernel.
__global__ __launch_bounds__(THREADS) void k_zero(uint4* __restrict__ ws4,
                                                  size_t n4, float* __restrict__ out)
{
    size_t i = (size_t)blockIdx.x * THREADS + threadIdx.x;
    if (i < n4) ws4[i] = make_uint4(0u, 0u, 0u, 0u);
    if (i == 0) out[0] = 0.f;
}

__global__ __launch_bounds__(THREADS) void k_hist1(
    const float* __restrict__ gt_r, const float* __restrict__ gt_a,
    const float* __restrict__ pr_r, const float* __restrict__ pr_a,
    const float* __restrict__ conf,
    unsigned int* __restrict__ h1c, float* __restrict__ h1s,
    unsigned int* __restrict__ stats_u, float* __restrict__ stats_f,
    unsigned int* __restrict__ l_buf)
{
    __shared__ unsigned long long s_hist[BINS * REPL];   // 16 KB, (cnt<<46)|sum_fx
    __shared__ unsigned int s_pc;
    __shared__ float s_ps;
    const int tid = threadIdx.x;
    const int row = blockIdx.y;
    const int samp = row & (NSAMP - 1);
    const float* gt = (row < NSAMP) ? gt_r : gt_a;
    const float* pr = (row < NSAMP) ? pr_r : pr_a;
    const unsigned copy = tid & (REPL - 1);

    for (int i = tid; i < BINS * REPL; i += THREADS) s_hist[i] = 0ULL;
    if (tid == 0) { s_pc = 0u; s_ps = 0.f; }
    __syncthreads();

    size_t base = (size_t)samp * NPIX + (size_t)blockIdx.x * EPB;
    size_t lbase = (size_t)row * NPIX + (size_t)blockIdx.x * EPB;
    unsigned int pc = 0; float ps = 0.f;
    #pragma unroll
    for (int it = 0; it < EPB / (THREADS * 4); ++it) {
        size_t idx = base + (size_t)it * THREADS * 4 + (size_t)tid * 4;
        float4 g = *(const float4*)(gt + idx);
        float4 p = *(const float4*)(pr + idx);
        float4 c = *(const float4*)(conf + idx);
        float gv[4] = {g.x, g.y, g.z, g.w};
        float pv[4] = {p.x, p.y, p.z, p.w};
        float cv[4] = {c.x, c.y, c.z, c.w};
        unsigned lb[4];
        #pragma unroll
        for (int j = 0; j < 4; ++j) {
            float d = pv[j] - gv[j];
            float l = d * d * cv[j];
            if (gv[j] >= 0.1f) {
                pc++; ps += l;
                lb[j] = 0xFFFFFFFFu;                  // sentinel: not a negative
            } else {
                unsigned bits = __float_as_uint(l);
                lb[j] = bits;
                unsigned bin = bits >> 20;            // l in [0,1) -> bin <= 1015
                unsigned long long pk =
                    (1ULL << 46) | (unsigned long long)(unsigned)(l * FXSCALE);
                atomicAdd(&s_hist[(bin << 1) | copy], pk);
            }
        }
        if (l_buf) {
            uint4 st = make_uint4(lb[0], lb[1], lb[2], lb[3]);
            *(uint4*)(l_buf + lbase + (size_t)it * THREADS * 4 + (size_t)tid * 4) = st;
        }
    }
    // wave-reduce the positive accumulators, then one LDS atomic per wave
    for (int off = 32; off; off >>= 1) {
        pc += __shfl_down(pc, off);
        ps += __shfl_down(ps, off);
    }
    if ((tid & 63) == 0) { atomicAdd(&s_pc, pc); atomicAdd(&s_ps, ps); }
    __syncthreads();

    for (int i = tid; i < BINS; i += THREADS) {
        unsigned long long v = s_hist[i << 1] + s_hist[(i << 1) | 1];
        if (v) {
            unsigned cnt = (unsigned)(v >> 46);
            float sum = (float)((double)(v & MASK46) * FXINV);
            atomicAdd(&h1c[row * BINS + i], cnt);
            atomicAdd(&h1s[row * BINS + i], sum);
        }
    }
    if (tid == 0) {
        if (s_pc) atomicAdd(&stats_u[row * STATS_STRIDE + 0], s_pc);
        if (s_ps != 0.f) atomicAdd(&stats_f[row * STATS_STRIDE + 1], s_ps);
    }
}

// Parallel descending-order boundary search over a 1024-bin histogram.
// Each thread owns 4 consecutive descending ranks (rank 0 = bin 1023).
// Finds the unique rank where cum (strictly above) < k <= cum+c.
__device__ __forceinline__ void suffix_scan_match(
    const unsigned int* __restrict__ hc, const float* __restrict__ hs,
    int row, unsigned k,
    bool* match, int* out_bin, unsigned* out_cum, float* out_sum,
    unsigned* out_c, float* out_s)
{
    const int tid = threadIdx.x;
    unsigned c[4]; float s[4];
    #pragma unroll
    for (int j = 0; j < 4; ++j) {
        int bin = BINS - 1 - (tid * 4 + j);
        c[j] = hc[row * BINS + bin];
        s[j] = hs[row * BINS + bin];
    }
    unsigned tc = c[0] + c[1] + c[2] + c[3];
    float    ts = s[0] + s[1] + s[2] + s[3];
    unsigned lane = tid & 63, w = tid >> 6;
    unsigned ic = tc; float is = ts;
    #pragma unroll
    for (int off = 1; off < 64; off <<= 1) {
        unsigned uc = __shfl_up(ic, off);
        float    us = __shfl_up(is, off);
        if (lane >= off) { ic += uc; is += us; }
    }
    __shared__ unsigned wtc[4]; __shared__ float wts[4];
    if (lane == 63) { wtc[w] = ic; wts[w] = is; }
    __syncthreads();
    unsigned woc = 0; float wos = 0.f;
    for (unsigned i = 0; i < w; ++i) { woc += wtc[i]; wos += wts[i]; }
    unsigned before_c = woc + ic - tc;  // exclusive prefix (count above my first rank)
    float    before_s = wos + is - ts;

    *match = false;
    #pragma unroll
    for (int j = 0; j < 4; ++j) {
        if (before_c < k && before_c + c[j] >= k) {
            *match = true;
            *out_bin = BINS - 1 - (tid * 4 + j);
            *out_cum = before_c;
            *out_sum = before_s;
            *out_c = c[j];
            *out_s = s[j];
        }
        before_c += c[j]; before_s += s[j];
    }
}

__global__ __launch_bounds__(THREADS) void k_sel1(
    const unsigned int* __restrict__ h1c, const float* __restrict__ h1s,
    unsigned int* __restrict__ stats_u, float* __restrict__ stats_f)
{
    const int row = blockIdx.x, tid = threadIdx.x;
    unsigned n_pos = stats_u[row * STATS_STRIDE + 0];
    unsigned n_neg = NPIX - n_pos;
    unsigned k;
    if (n_pos > 0u) {
        k = 3u * n_pos;
        if (k > n_neg) k = n_neg;
        if (k < 1u) k = 1u;
    } else {
        k = 500u;   // fallback: top-500 over all pixels (all are "negatives" here)
    }
    if (tid == 0) stats_u[row * STATS_STRIDE + 2] = k;
    if (n_neg == 0u) {
        if (tid == 0) stats_u[row * STATS_STRIDE + 6] = 0xFFFFFFFFu;
        return;
    }
    bool match; int b1; unsigned cum, cb; float sum, sb;
    suffix_scan_match(h1c, h1s, row, k, &match, &b1, &cum, &sum, &cb, &sb);
    if (match) {
        stats_u[row * STATS_STRIDE + 3] = (unsigned)b1;
        stats_u[row * STATS_STRIDE + 4] = cum;
        stats_f[row * STATS_STRIDE + 5] = sum;
        stats_u[row * STATS_STRIDE + 6] = k - cum;   // k' >= 1
    }
}

__global__ __launch_bounds__(THREADS) void k_hist2(
    const float* __restrict__ gt_r, const float* __restrict__ gt_a,
    const float* __restrict__ pr_r, const float* __restrict__ pr_a,
    const float* __restrict__ conf,
    unsigned int* __restrict__ h2c, float* __restrict__ h2s,
    const unsigned int* __restrict__ stats_u,
    const unsigned int* __restrict__ l_buf)
{
    __shared__ unsigned int s_cnt[BINS];
    __shared__ float s_sum[BINS];
    const int tid = threadIdx.x;
    const int row = blockIdx.y;
    const unsigned kprime = stats_u[row * STATS_STRIDE + 6];
    if (kprime == 0xFFFFFFFFu) return;      // uniform per block
    const unsigned b1 = stats_u[row * STATS_STRIDE + 3];

    for (int i = tid; i < BINS; i += THREADS) { s_cnt[i] = 0u; s_sum[i] = 0.f; }
    __syncthreads();

    if (l_buf) {
        size_t lbase = (size_t)row * NPIX + (size_t)blockIdx.x * EPB;
        #pragma unroll
        for (int it = 0; it < EPB / (THREADS * 4); ++it) {
            uint4 bv = *(const uint4*)(l_buf + lbase + (size_t)it * THREADS * 4
                                       + (size_t)tid * 4);
            unsigned b[4] = {bv.x, bv.y, bv.z, bv.w};
            #pragma unroll
            for (int j = 0; j < 4; ++j) {
                if ((b[j] >> 20) == b1) {
                    unsigned bin2 = (b[j] >> 10) & 1023u;
                    atomicAdd(&s_cnt[bin2], 1u);
                    atomicAdd(&s_sum[bin2], __uint_as_float(b[j]));
                }
            }
        }
    } else {
        const int samp = row & (NSAMP - 1);
        const float* gt = (row < NSAMP) ? gt_r : gt_a;
        const float* pr = (row < NSAMP) ? pr_r : pr_a;
        size_t base = (size_t)samp * NPIX + (size_t)blockIdx.x * EPB;
        #pragma unroll
        for (int it = 0; it < EPB / (THREADS * 4); ++it) {
            size_t idx = base + (size_t)it * THREADS * 4 + (size_t)tid * 4;
            float4 g = *(const float4*)(gt + idx);
            float4 p = *(const float4*)(pr + idx);
            float4 c = *(const float4*)(conf + idx);
            float gv[4] = {g.x, g.y, g.z, g.w};
            float pv[4] = {p.x, p.y, p.z, p.w};
            float cv[4] = {c.x, c.y, c.z, c.w};
            #pragma unroll
            for (int j = 0; j < 4; ++j) {
                float d = pv[j] - gv[j];
                float l = d * d * cv[j];
                if (gv[j] < 0.1f) {
                    unsigned bits = __float_as_uint(l);
                    if ((bits >> 20) == b1) {
                        unsigned bin2 = (bits >> 10) & 1023u;
                        atomicAdd(&s_cnt[bin2], 1u);
                        atomicAdd(&s_sum[bin2], l);
                    }
                }
            }
        }
    }
    __syncthreads();
    for (int i = tid; i < BINS; i += THREADS) {
        unsigned c = s_cnt[i];
        if (c) {
            atomicAdd(&h2c[row * BINS + i], c);
            atomicAdd(&h2s[row * BINS + i], s_sum[i]);
        }
    }
}

// Computes the per-row result and accumulates it directly into d_out
// (zeroed by k_zero). Removes the separate k_final launch.
__global__ __launch_bounds__(THREADS) void k_sel2(
    const unsigned int* __restrict__ h2c, const float* __restrict__ h2s,
    const unsigned int* __restrict__ stats_u, const float* __restrict__ stats_f,
    float* __restrict__ out)
{
    const int row = blockIdx.x, tid = threadIdx.x;
    unsigned n_pos = stats_u[row * STATS_STRIDE + 0];
    unsigned k     = stats_u[row * STATS_STRIDE + 2];
    float pos_part = (n_pos > 0u) ? stats_f[row * STATS_STRIDE + 1] / (float)n_pos : 0.f;
    unsigned kprime = stats_u[row * STATS_STRIDE + 6];
    if (kprime == 0xFFFFFFFFu) {
        if (tid == 0) atomicAdd(out, (pos_part - 1.f) / (float)NSAMP); // sentinel
        return;
    }
    bool match; int b2; unsigned cum, cb; float sum, sb;
    suffix_scan_match(h2c, h2s, row, kprime, &match, &b2, &cum, &sum, &cb, &sb);
    if (match) {
        unsigned kpp = kprime - cum;           // 1 <= kpp <= cnt[b2]
        float mean = sb / (float)cb;
        float topk = stats_f[row * STATS_STRIDE + 5] + sum + (float)kpp * mean;
        atomicAdd(out, (pos_part + topk / (float)k) / (float)NSAMP);
    }
}

extern "C" void kernel_launch(void* const* d_in, const int* in_sizes, int n_in,
                              void* d_out, int out_size, void* d_ws, size_t ws_size,
                              hipStream_t stream)
{
    (void)in_sizes; (void)n_in; (void)out_size;
    const float* gt_r = (const float*)d_in[0];
    const float* gt_a = (const float*)d_in[1];
    const float* pr_r = (const float*)d_in[2];
    const float* pr_a = (const float*)d_in[3];
    const float* conf = (const float*)d_in[4];

    char* ws = (char*)d_ws;
    unsigned int* h1c = (unsigned int*)(ws + 0 * (size_t)ROWS * BINS * 4);
    float*        h1s = (float*)       (ws + 1 * (size_t)ROWS * BINS * 4);
    unsigned int* h2c = (unsigned int*)(ws + 2 * (size_t)ROWS * BINS * 4);
    float*        h2s = (float*)       (ws + 3 * (size_t)ROWS * BINS * 4);
    unsigned int* stats_u = (unsigned int*)(ws + 4 * (size_t)ROWS * BINS * 4);
    float*        stats_f = (float*)       (ws + 4 * (size_t)ROWS * BINS * 4);
    size_t hist_used = 4 * (size_t)ROWS * BINS * 4 + (size_t)ROWS * STATS_STRIDE * 4;

    const size_t L_OFF = 2u << 20;                       // 2 MB, past hist region
    const size_t L_BYTES = (size_t)ROWS * NPIX * 4;      // 37.75 MB
    unsigned int* l_buf = (ws_size >= L_OFF + L_BYTES)
                        ? (unsigned int*)(ws + L_OFF) : nullptr;

    size_t n4 = hist_used / 16;                          // uint4 count (divisible)
    int zblocks = (int)((n4 + THREADS - 1) / THREADS);
    k_zero<<<zblocks, THREADS, 0, stream>>>((uint4*)ws, n4, (float*)d_out);

    dim3 gridA(BLKROW, ROWS);
    k_hist1<<<gridA, THREADS, 0, stream>>>(gt_r, gt_a, pr_r, pr_a, conf,
                                           h1c, h1s, stats_u, stats_f, l_buf);
    k_sel1<<<ROWS, THREADS, 0, stream>>>(h1c, h1s, stats_u, stats_f);
    k_hist2<<<gridA, THREADS, 0, stream>>>(gt_r, gt_a, pr_r, pr_a, conf,
                                           h2c, h2s, stats_u, l_buf);
    k_sel2<<<ROWS, THREADS, 0, stream>>>(h2c, h2s, stats_u, stats_f, (float*)d_out);
}